// Round 4
// baseline (65.674 us; speedup 1.0000x reference)
//
#include <hip/hip_runtime.h>

#define LSEQ 4096

typedef __bf16 bf16x8 __attribute__((ext_vector_type(8)));
typedef float f32x16 __attribute__((ext_vector_type(16)));

union FU { unsigned u[4]; uint4 u4; bf16x8 v; };

__device__ __forceinline__ unsigned short bfb(float f) {
  __bf16 h = (__bf16)f;
  return __builtin_bit_cast(unsigned short, h);
}
__device__ __forceinline__ unsigned pk2(float a, float b) {
  return (unsigned)bfb(a) | ((unsigned)bfb(b) << 16);
}
// Half-exchange across lane 32 boundary (verified rounds 0-3).
__device__ __forceinline__ void xchg(unsigned P0, unsigned P1, unsigned P2, unsigned P3,
                                     const int hi, unsigned o[4]) {
  const unsigned sA = hi ? P0 : P2, sB = hi ? P1 : P3;
  const unsigned rA = __shfl_xor(sA, 32), rB = __shfl_xor(sB, 32);
  o[0] = hi ? rA : P0; o[1] = hi ? rB : P1;
  o[2] = hi ? P2 : rA; o[3] = hi ? P3 : rB;
}

// Batch-issue the 9 weight fragments (8 K-steps + bias) for (mat, nt).
__device__ __forceinline__ void loadW(const uint4* __restrict__ wf4, int mat, int nt,
                                      int l, FU w[9]) {
#pragma unroll
  for (int ks = 0; ks < 9; ++ks)
    w[ks].u4 = wf4[((mat * 4 + nt) * 9 + ks) * 64 + l];
}

// Repack weights to fragment order in ws: frag[((m*4+nt)*9+ks)*64 + lane],
// frag[l][e] = W[ks*16 + 8*(l>>5) + e][nt*32 + (l&31)]; ks==8 is the bias
// outer-product fragment (bias at k-offset 0).
__global__ __launch_bounds__(64) void repack(
    const float* __restrict__ Wv, const float* __restrict__ bv,
    const float* __restrict__ Wk, const float* __restrict__ bk,
    const float* __restrict__ Wq, const float* __restrict__ bq,
    const float* __restrict__ Wo, const float* __restrict__ bo,
    uint4* __restrict__ ws) {
  const int b = blockIdx.x;  // 144 = 4 mats * 4 nt * 9 ks
  const int ks = b % 9, nt = (b / 9) & 3, m = b / 36;
  const float* Ws[4] = {Wv, Wk, Wq, Wo};
  const float* Bs[4] = {bv, bk, bq, bo};
  const int l = threadIdx.x, l31 = l & 31, hi = l >> 5;
  FU f;
  if (ks < 8) {
#pragma unroll
    for (int e = 0; e < 4; ++e) {
      const float a = Ws[m][(ks * 16 + hi * 8 + 2 * e) * 128 + nt * 32 + l31];
      const float c = Ws[m][(ks * 16 + hi * 8 + 2 * e + 1) * 128 + nt * 32 + l31];
      f.u[e] = pk2(a, c);
    }
  } else {
    f.u[0] = (hi == 0) ? (unsigned)bfb(Bs[m][nt * 32 + l31]) : 0u;
    f.u[1] = 0; f.u[2] = 0; f.u[3] = 0;
  }
  ws[b * 64 + l] = f.u4;
}

// One t per block. 4 waves; wave nt owns output cols [nt*32, nt*32+32)
// (= heads 2nt, 2nt+1). X staged in LDS (XOR-swizzled fragment layout);
// weight fragments register-prefetched one projection ahead from L2.
__global__ __launch_bounds__(256, 3) void fused_mha(
    const float* __restrict__ Xv, const float* __restrict__ Xk, const float* __restrict__ Xq,
    const uint4* __restrict__ wf4, float* __restrict__ out) {
  __shared__ uint4 xlds[3 * 8 * 64];  // 24KB: [tau][ks][lane^ks]
  __shared__ uint4 olds[8 * 64];      // 8KB:  [h][lane]
  const int tid = threadIdx.x;
  const int t = blockIdx.x;
  const int wid = tid >> 6, l = tid & 63;
  const int nt = wid, l31 = l & 31, hi = l >> 5;

  // Prefetch V + K weight fragments; they drain together with the X loads.
  FU wfA[9], wfB[9];
  loadW(wf4, 0, nt, l, wfA);
  loadW(wf4, 1, nt, l, wfB);

  {  // cooperative X stage: thread = (row r, k-chunk ksc), 64B contiguous
    const int r = tid >> 3, ksc = tid & 7;
    const float* Xs[3] = {Xv, Xk, Xq};
#pragma unroll
    for (int tau = 0; tau < 3; ++tau) {
      const float4* p4 = reinterpret_cast<const float4*>(
          Xs[tau] + ((long)r * LSEQ + t) * 128 + ksc * 16);
      const float4 a = p4[0], b = p4[1], c = p4[2], d = p4[3];
      FU lo, hb;
      lo.u[0] = pk2(a.x, a.y); lo.u[1] = pk2(a.z, a.w);
      lo.u[2] = pk2(b.x, b.y); lo.u[3] = pk2(b.z, b.w);
      hb.u[0] = pk2(c.x, c.y); hb.u[1] = pk2(c.z, c.w);
      hb.u[2] = pk2(d.x, d.y); hb.u[3] = pk2(d.z, d.w);
      xlds[(tau * 8 + ksc) * 64 + (r ^ ksc)] = lo.u4;         // hi=0 half
      xlds[(tau * 8 + ksc) * 64 + ((r ^ ksc) | 32)] = hb.u4;  // hi=1 half
    }
  }
  __syncthreads();

  FU cf;  // constant frag: 1.0 at k-offset 0 (bias K-step)
  cf.u[0] = hi ? 0u : 0x00003F80u; cf.u[1] = 0; cf.u[2] = 0; cf.u[3] = 0;

  unsigned vpk[8];
  FU kf[2], qf[2];

  {  // ---- V projection (option A: acc = X@Wv tile), mat 0, consumes wfA ----
    f32x16 acc = {};
#pragma unroll
    for (int ks = 0; ks < 8; ++ks) {
      FU xf; xf.u4 = xlds[(0 * 8 + ks) * 64 + (l ^ ks)];
      acc = __builtin_amdgcn_mfma_f32_32x32x16_bf16(xf.v, wfA[ks].v, acc, 0, 0, 0);
    }
    acc = __builtin_amdgcn_mfma_f32_32x32x16_bf16(cf.v, wfA[8].v, acc, 0, 0, 0);
#pragma unroll
    for (int jv = 0; jv < 8; ++jv) vpk[jv] = pk2(acc[2 * jv], acc[2 * jv + 1]);
  }

  loadW(wf4, 2, nt, l, wfA);  // prefetch Q frags under K-proj compute

  {  // ---- K projection (option B: K^T tiles), mat 1, consumes wfB ----
    f32x16 acc = {};
#pragma unroll
    for (int ks = 0; ks < 8; ++ks) {
      FU xf; xf.u4 = xlds[(1 * 8 + ks) * 64 + (l ^ ks)];
      acc = __builtin_amdgcn_mfma_f32_32x32x16_bf16(wfB[ks].v, xf.v, acc, 0, 0, 0);
    }
    acc = __builtin_amdgcn_mfma_f32_32x32x16_bf16(wfB[8].v, cf.v, acc, 0, 0, 0);
#pragma unroll
    for (int ch = 0; ch < 2; ++ch) {
      const int c8 = ch * 8;
      xchg(pk2(acc[c8 + 0], acc[c8 + 1]), pk2(acc[c8 + 2], acc[c8 + 3]),
           pk2(acc[c8 + 4], acc[c8 + 5]), pk2(acc[c8 + 6], acc[c8 + 7]), hi, kf[ch].u);
    }
  }

  loadW(wf4, 3, nt, l, wfB);  // prefetch O frags; hidden under Q-proj + attention

  {  // ---- Q projection (option B), mat 2, consumes wfA ----
    f32x16 acc = {};
#pragma unroll
    for (int ks = 0; ks < 8; ++ks) {
      FU xf; xf.u4 = xlds[(2 * 8 + ks) * 64 + (l ^ ks)];
      acc = __builtin_amdgcn_mfma_f32_32x32x16_bf16(wfA[ks].v, xf.v, acc, 0, 0, 0);
    }
    acc = __builtin_amdgcn_mfma_f32_32x32x16_bf16(wfA[8].v, cf.v, acc, 0, 0, 0);
#pragma unroll
    for (int ch = 0; ch < 2; ++ch) {
      const int c8 = ch * 8;
      xchg(pk2(acc[c8 + 0], acc[c8 + 1]), pk2(acc[c8 + 2], acc[c8 + 3]),
           pk2(acc[c8 + 4], acc[c8 + 5]), pk2(acc[c8 + 6], acc[c8 + 7]), hi, qf[ch].u);
    }
  }

  {  // ---- batch-axis attention for heads 2nt, 2nt+1 ----
    FU vm0, vm1, vs0, vs1;
    xchg(vpk[0], vpk[1], vpk[2], vpk[3], hi, vm0.u);
    xchg(vpk[4], vpk[5], vpk[6], vpk[7], hi, vm1.u);
#pragma unroll
    for (int i = 0; i < 4; ++i) {
      vs0.u[i] = __shfl_xor(vm0.u[i], 16);
      vs1.u[i] = __shfl_xor(vm1.u[i], 16);
    }
#pragma unroll
    for (int ch = 0; ch < 2; ++ch) {
      const int h = nt * 2 + ch;
      const bool own = ((l31 >> 4) == ch);
      f32x16 zz = {};
      f32x16 S = __builtin_amdgcn_mfma_f32_32x32x16_bf16(kf[ch].v, qf[ch].v, zz, 0, 0, 0);
      float mx = S[0];
#pragma unroll
      for (int r = 1; r < 16; ++r) mx = fmaxf(mx, S[r]);
      mx = fmaxf(mx, __shfl_xor(mx, 32));
      float p[16], sum = 0.f;
#pragma unroll
      for (int r = 0; r < 16; ++r) {
        p[r] = exp2f((S[r] - mx) * 1.44269504089f);
        sum += p[r];
      }
      sum += __shfl_xor(sum, 32);
      const float inv = 1.0f / sum;
      FU pf0, pf1;
      xchg(pk2(p[0], p[1]), pk2(p[2], p[3]), pk2(p[4], p[5]), pk2(p[6], p[7]), hi, pf0.u);
      xchg(pk2(p[8], p[9]), pk2(p[10], p[11]), pk2(p[12], p[13]), pk2(p[14], p[15]), hi, pf1.u);
      FU v0, v1;
#pragma unroll
      for (int i = 0; i < 4; ++i) {
        v0.u[i] = own ? vm0.u[i] : vs0.u[i];
        v1.u[i] = own ? vm1.u[i] : vs1.u[i];
      }
      f32x16 z2 = {};
      f32x16 Ot = __builtin_amdgcn_mfma_f32_32x32x16_bf16(v0.v, pf0.v, z2, 0, 0, 0);
      Ot = __builtin_amdgcn_mfma_f32_32x32x16_bf16(v1.v, pf1.v, Ot, 0, 0, 0);
      FU ofr;
      xchg(pk2(Ot[0] * inv, Ot[1] * inv), pk2(Ot[2] * inv, Ot[3] * inv),
           pk2(Ot[4] * inv, Ot[5] * inv), pk2(Ot[6] * inv, Ot[7] * inv), hi, ofr.u);
      olds[h * 64 + l] = ofr.u4;
    }
  }
  __syncthreads();

  {  // ---- output projection (option A over 8 head K-steps), mat 3, consumes wfB ----
    f32x16 acc = {};
#pragma unroll
    for (int h = 0; h < 8; ++h) {
      FU of; of.u4 = olds[h * 64 + l];
      acc = __builtin_amdgcn_mfma_f32_32x32x16_bf16(of.v, wfB[h].v, acc, 0, 0, 0);
    }
    acc = __builtin_amdgcn_mfma_f32_32x32x16_bf16(cf.v, wfB[8].v, acc, 0, 0, 0);
#pragma unroll
    for (int r = 0; r < 16; ++r) {
      const int n = (r & 3) + ((r >> 2) << 3) + (hi << 2);
      out[((long)n * LSEQ + t) * 128 + nt * 32 + l31] = acc[r];
    }
  }
}

extern "C" void kernel_launch(void* const* d_in, const int* in_sizes, int n_in,
                              void* d_out, int out_size, void* d_ws, size_t ws_size,
                              hipStream_t stream) {
  const float* values  = (const float*)d_in[0];
  const float* keys    = (const float*)d_in[1];
  const float* queries = (const float*)d_in[2];
  const float* Wv = (const float*)d_in[3];
  const float* bv = (const float*)d_in[4];
  const float* Wk = (const float*)d_in[5];
  const float* bk = (const float*)d_in[6];
  const float* Wq = (const float*)d_in[7];
  const float* bq = (const float*)d_in[8];
  const float* Wo = (const float*)d_in[9];
  const float* bo = (const float*)d_in[10];

  repack<<<dim3(144), dim3(64), 0, stream>>>(Wv, bv, Wk, bk, Wq, bq, Wo, bo,
                                             (uint4*)d_ws);
  fused_mha<<<dim3(LSEQ), dim3(256), 0, stream>>>(
      values, keys, queries, (const uint4*)d_ws, (float*)d_out);
}